// Round 10
// baseline (337.574 us; speedup 1.0000x reference)
//
#include <hip/hip_runtime.h>
#include <math.h>

#define T_SEQ  2048
#define DMODEL 2048
#define NHEADS 16
#define HDIM   128
#define MROWS  4096   // B*T

typedef __attribute__((ext_vector_type(8)))  __bf16 bf16x8;
typedef __attribute__((ext_vector_type(4)))  __bf16 bf16x4;
typedef __attribute__((ext_vector_type(4)))  float  f32x4;
typedef __attribute__((ext_vector_type(16))) float  f32x16;
typedef __attribute__((ext_vector_type(4)))  unsigned int uint32x4;

#define GLOBAL_AS __attribute__((address_space(1)))
#define LDS_AS    __attribute__((address_space(3)))
__device__ __forceinline__ void async_copy16(const __bf16* g, __bf16* l) {
  // 16B/lane, LDS dest = wave-uniform base + lane*16 (m97/m104 semantics)
  __builtin_amdgcn_global_load_lds((const GLOBAL_AS void*)g, (LDS_AS void*)l, 16, 0, 0);
}

// pack two fp32 -> one u32 of 2 bf16 (RNE via (__bf16) cast)
__device__ __forceinline__ unsigned int pack_bf16_2(float a, float b) {
  __bf16 x = (__bf16)a, y = (__bf16)b;
  unsigned short ux = __builtin_bit_cast(unsigned short, x);
  unsigned short uy = __builtin_bit_cast(unsigned short, y);
  return (unsigned int)ux | ((unsigned int)uy << 16);
}

// ---------------------------------------------------------------------------
// Merged prep kernel, region-dispatched by blockIdx.x (unchanged).
// ---------------------------------------------------------------------------
__global__ __launch_bounds__(256) void prep_kernel(
    const float* __restrict__ x,
    const float* __restrict__ Wq, const float* __restrict__ Wk,
    const float* __restrict__ Wv, const float* __restrict__ Wo,
    float2* __restrict__ rope, __bf16* __restrict__ xb,
    __bf16* __restrict__ wqkvt, __bf16* __restrict__ wot)
{
  __shared__ float t[32][33];
  const int bid = blockIdx.x;
  const int tid = threadIdx.x;

  if (bid < 512) {                       // ---- RoPE table ----
    int idx = bid*256 + tid;             // 2048*64 entries
    int d = idx & 63, pos = idx >> 6;
    double freq = pow(10000.0, -(double)d / 64.0);
    double ang = (double)pos * freq;
    rope[idx] = make_float2((float)cos(ang), (float)sin(ang));
    return;
  }
  if (bid < 512 + 8192) {                // ---- x fp32 -> bf16 ----
    int i = (bid - 512)*256 + tid;       // n4 = 4096*2048/4 = 2097152 exactly
    float4 v = ((const float4*)x)[i];
    bf16x4 o = { (__bf16)v.x, (__bf16)v.y, (__bf16)v.z, (__bf16)v.w };
    *(bf16x4*)(xb + (size_t)i*4) = o;
    return;
  }
  // ---- weight transpose-cast (region grid 136 x 64) ----
  const int lb = bid - (512 + 8192);     // [0, 8704)
  const int by = lb / 136;               // row-tile 0..63
  const int bx = lb - by*136;            // col/region tile 0..135
  const float* src; __bf16* dst; int istride, c0, orow;
  if (bx < 64)       { src = Wq; istride = 2048; c0 = bx*32;      orow = c0;        dst = wqkvt; }
  else if (bx < 68)  { src = Wk; istride = 128;  c0 = (bx-64)*32; orow = 2048 + c0; dst = wqkvt; }
  else if (bx < 72)  { src = Wv; istride = 128;  c0 = (bx-68)*32; orow = 2176 + c0; dst = wqkvt; }
  else               { src = Wo; istride = 2048; c0 = (bx-72)*32; orow = c0;        dst = wot; }
  const int tx = tid & 31, ty = tid >> 5;
  const int r0 = by*32;
#pragma unroll
  for (int i = 0; i < 4; ++i)
    t[ty + i*8][tx] = src[(size_t)(r0 + ty + i*8)*istride + c0 + tx];
  __syncthreads();
#pragma unroll
  for (int i = 0; i < 4; ++i)
    dst[(size_t)(orow + ty + i*8)*2048 + r0 + tx] = (__bf16)t[tx][ty + i*8];
}

// ---------------------------------------------------------------------------
// bf16 -> bf16 transpose for V: in [B][2048][128] -> out [B][128][2048].
// ---------------------------------------------------------------------------
__global__ void transpose_v_kernel(const __bf16* __restrict__ in,
                                   __bf16* __restrict__ out) {
  __shared__ __bf16 t[32][34];
  const int bz = blockIdx.z;
  in  += (size_t)bz * 2048 * 128;
  out += (size_t)bz * 128 * 2048;
  const int tx = threadIdx.x & 31, ty = threadIdx.x >> 5;
  const int r0 = blockIdx.y*32, c0 = blockIdx.x*32;
#pragma unroll
  for (int i = 0; i < 4; ++i)
    t[ty + i*8][tx] = in[(size_t)(r0 + ty + i*8)*128 + c0 + tx];
  __syncthreads();
#pragma unroll
  for (int i = 0; i < 4; ++i)
    out[(size_t)(c0 + ty + i*8)*2048 + r0 + tx] = t[tx][ty + i*8];
}

// ---------------------------------------------------------------------------
// Fused QKV GEMM — R10: EXACT R4 body (single-buffer m97, BK=32, grid
// (18,32), linear V to vbb). CONTROL arm — best measured config (R4: 312.4).
// ---------------------------------------------------------------------------
__global__ __launch_bounds__(256) void gemm_qkv_fused(
    const __bf16* __restrict__ A,      // xb [4096][2048]
    const __bf16* __restrict__ Bt,     // wqkvt [2304][2048]
    const float* __restrict__ bq, const float* __restrict__ bk,
    const float* __restrict__ bv,
    const float2* __restrict__ rope,   // [2048][64]
    __bf16* __restrict__ qrb,          // [4096][2048]
    __bf16* __restrict__ kbb,          // [4096][128]
    __bf16* __restrict__ vbb,          // [4096][128]
    float qscale)
{
  __shared__ __bf16 As[128*32];
  __shared__ __bf16 Bs[128*32];
  const int bx = blockIdx.x, by = blockIdx.y;
  const int tid = threadIdx.x;
  const int lane = tid & 63, wave = tid >> 6;
  const int quad = lane >> 4, l16 = lane & 15;
  const int m0 = (wave >> 1)*64, n0 = (wave & 1)*32;
  const int row0 = by*128, col0 = bx*128;
  const int srow = lane >> 2, scol = (lane & 3)*8;

  f32x4 acc[4][4];
#pragma unroll
  for (int i = 0; i < 4; ++i)
#pragma unroll
    for (int j = 0; j < 4; ++j) acc[i][j] = (f32x4){0.f,0.f,0.f,0.f};

  const __bf16* Ag = A  + (size_t)(row0 + wave*32 + srow)*DMODEL + scol;
  const __bf16* Bg = Bt + (size_t)(col0 + wave*32 + srow)*DMODEL + scol;
  __bf16* AsW = &As[wave*1024];
  __bf16* BsW = &Bs[wave*1024];

  for (int kk = 0; kk < DMODEL; kk += 32) {
    __syncthreads();
    async_copy16(Ag + kk,                     AsW);
    async_copy16(Ag + kk + (size_t)16*DMODEL, AsW + 512);
    async_copy16(Bg + kk,                     BsW);
    async_copy16(Bg + kk + (size_t)16*DMODEL, BsW + 512);
    __syncthreads();
    bf16x8 af[4], bfr[4];
#pragma unroll
    for (int i = 0; i < 4; ++i)
      af[i] = *(const bf16x8*)&As[(m0 + i*16 + l16)*32 + quad*8];
#pragma unroll
    for (int j = 0; j < 4; ++j) {
      const int cb = n0 + (j & 1)*16 + (j >> 1)*64;   // remapped column base
      bfr[j] = *(const bf16x8*)&Bs[(cb + l16)*32 + quad*8];
    }
#pragma unroll
    for (int i = 0; i < 4; ++i)
#pragma unroll
      for (int j = 0; j < 4; ++j)
        acc[i][j] = __builtin_amdgcn_mfma_f32_16x16x32_bf16(af[i], bfr[j], acc[i][j], 0,0,0);
  }

  // ---- fused epilogue: bias + RoPE + scale + bf16 store -------------------
  const float* bias_p; float scale; bool rot; __bf16* obase; int ostride;
  if (bx < 16)      { bias_p = bq + bx*128; scale = qscale; rot = true;
                      obase = qrb + bx*128; ostride = 2048; }
  else if (bx == 16){ bias_p = bk; scale = 1.f; rot = true;
                      obase = kbb; ostride = 128; }
  else              { bias_p = bv; scale = 1.f; rot = false;
                      obase = vbb; ostride = 128; }

#pragma unroll
  for (int j = 0; j < 2; ++j) {
    const int d = n0 + j*16 + l16;        // 0..63 within the 128-wide region
    const float b1 = bias_p[d], b2 = bias_p[d + 64];
#pragma unroll
    for (int i = 0; i < 4; ++i) {
      const int rl = m0 + i*16 + quad*4;
#pragma unroll
      for (int r = 0; r < 4; ++r) {
        const int rg = row0 + rl + r;
        const float x1 = acc[i][j][r]   + b1;
        const float x2 = acc[i][j+2][r] + b2;
        float c = 1.f, s = 0.f;
        if (rot) { float2 cs = rope[(size_t)(rg & (T_SEQ-1))*64 + d]; c = cs.x; s = cs.y; }
        obase[(size_t)rg*ostride + d]      = (__bf16)((x1*c - x2*s)*scale);
        obase[(size_t)rg*ostride + d + 64] = (__bf16)((x2*c + x1*s)*scale);
      }
    }
  }
}

// ---------------------------------------------------------------------------
// R10 TREATMENT: split-K=2 out-GEMM. Grid (N/128, M/128, 2); blockIdx.z picks
// K-half [z*1024,(z+1)*1024). Body = R4-exact m97 structure. Writes fp32
// partial (no bias). 1024 blocks = 4 blocks/CU (vs 2.0) — the m102 curve's
// occupancy lever — with UNCHANGED total A/B panel traffic.
// ---------------------------------------------------------------------------
__global__ __launch_bounds__(256) void gemm_out_splitk(
    const __bf16* __restrict__ A, const __bf16* __restrict__ Bt,
    float* __restrict__ pout)          // [2][4096][2048] fp32 partials
{
  __shared__ __bf16 As[128*32];
  __shared__ __bf16 Bs[128*32];
  const int tid = threadIdx.x;
  const int lane = tid & 63, wave = tid >> 6;
  const int quad = lane >> 4, l16 = lane & 15;
  const int m0 = (wave & 1)*64, n0 = (wave >> 1)*64;
  const int row0 = blockIdx.y*128, col0 = blockIdx.x*128;
  const int srow = lane >> 2, scol = (lane & 3)*8;
  const int kbase = blockIdx.z * (DMODEL/2);
  float* C = pout + (size_t)blockIdx.z * MROWS * DMODEL;

  f32x4 acc[4][4];
#pragma unroll
  for (int i = 0; i < 4; ++i)
#pragma unroll
    for (int j = 0; j < 4; ++j) acc[i][j] = (f32x4){0.f,0.f,0.f,0.f};

  const __bf16* Ag = A  + (size_t)(row0 + wave*32 + srow)*DMODEL + kbase + scol;
  const __bf16* Bg = Bt + (size_t)(col0 + wave*32 + srow)*DMODEL + kbase + scol;
  __bf16* AsW = &As[wave*1024];
  __bf16* BsW = &Bs[wave*1024];

  for (int kk = 0; kk < DMODEL/2; kk += 32) {
    __syncthreads();
    async_copy16(Ag + kk,                     AsW);
    async_copy16(Ag + kk + (size_t)16*DMODEL, AsW + 512);
    async_copy16(Bg + kk,                     BsW);
    async_copy16(Bg + kk + (size_t)16*DMODEL, BsW + 512);
    __syncthreads();
    bf16x8 af[4], bfr[4];
#pragma unroll
    for (int i = 0; i < 4; ++i)
      af[i] = *(const bf16x8*)&As[(m0 + i*16 + l16)*32 + quad*8];
#pragma unroll
    for (int j = 0; j < 4; ++j)
      bfr[j] = *(const bf16x8*)&Bs[(n0 + j*16 + l16)*32 + quad*8];
#pragma unroll
    for (int i = 0; i < 4; ++i)
#pragma unroll
      for (int j = 0; j < 4; ++j)
        acc[i][j] = __builtin_amdgcn_mfma_f32_16x16x32_bf16(af[i], bfr[j], acc[i][j], 0,0,0);
  }
#pragma unroll
  for (int j = 0; j < 4; ++j) {
    const int ccol = col0 + n0 + j*16 + l16;
#pragma unroll
    for (int i = 0; i < 4; ++i) {
      const int crow = row0 + m0 + i*16 + quad*4;
#pragma unroll
      for (int r = 0; r < 4; ++r)
        C[(size_t)(crow + r)*DMODEL + ccol] = acc[i][j][r];
    }
  }
}

// out = p0 + p1 + bias (float4-vectorized, deterministic 2-term add)
__global__ __launch_bounds__(256) void reduce_out_kernel(
    const float* __restrict__ pout, const float* __restrict__ bias,
    float* __restrict__ out)
{
  const size_t idx = (size_t)blockIdx.x*256 + threadIdx.x;  // float4 index
  float4 a = ((const float4*)pout)[idx];
  float4 b = ((const float4*)(pout + (size_t)MROWS*DMODEL))[idx];
  float4 bi = ((const float4*)bias)[idx & (DMODEL/4 - 1)];
  float4 o;
  o.x = a.x + b.x + bi.x; o.y = a.y + b.y + bi.y;
  o.z = a.z + b.z + bi.z; o.w = a.w + b.w + bi.w;
  ((float4*)out)[idx] = o;
}

// ---------------------------------------------------------------------------
// Fallback out-GEMM (R4-exact) if workspace too small for split-K partials.
// ---------------------------------------------------------------------------
__global__ __launch_bounds__(256) void gemm_bf16_t128(
    const __bf16* __restrict__ A, const __bf16* __restrict__ Bt,
    const float* __restrict__ bias, float* __restrict__ C,
    int M, int N, int K)
{
  __shared__ __bf16 As[128*32];
  __shared__ __bf16 Bs[128*32];
  const int tid = threadIdx.x;
  const int lane = tid & 63, wave = tid >> 6;
  const int quad = lane >> 4, l16 = lane & 15;
  const int m0 = (wave & 1)*64, n0 = (wave >> 1)*64;
  const int row0 = blockIdx.y*128, col0 = blockIdx.x*128;
  const int srow = lane >> 2, scol = (lane & 3)*8;

  f32x4 acc[4][4];
#pragma unroll
  for (int i = 0; i < 4; ++i)
#pragma unroll
    for (int j = 0; j < 4; ++j) acc[i][j] = (f32x4){0.f,0.f,0.f,0.f};

  const __bf16* Ag = A  + (size_t)(row0 + wave*32 + srow)*K + scol;
  const __bf16* Bg = Bt + (size_t)(col0 + wave*32 + srow)*K + scol;
  __bf16* AsW = &As[wave*1024];
  __bf16* BsW = &Bs[wave*1024];

  for (int kk = 0; kk < K; kk += 32) {
    __syncthreads();
    async_copy16(Ag + kk,              AsW);
    async_copy16(Ag + kk + (size_t)16*K, AsW + 512);
    async_copy16(Bg + kk,              BsW);
    async_copy16(Bg + kk + (size_t)16*K, BsW + 512);
    __syncthreads();
    bf16x8 af[4], bfr[4];
#pragma unroll
    for (int i = 0; i < 4; ++i)
      af[i] = *(const bf16x8*)&As[(m0 + i*16 + l16)*32 + quad*8];
#pragma unroll
    for (int j = 0; j < 4; ++j)
      bfr[j] = *(const bf16x8*)&Bs[(n0 + j*16 + l16)*32 + quad*8];
#pragma unroll
    for (int i = 0; i < 4; ++i)
#pragma unroll
      for (int j = 0; j < 4; ++j)
        acc[i][j] = __builtin_amdgcn_mfma_f32_16x16x32_bf16(af[i], bfr[j], acc[i][j], 0,0,0);
  }
#pragma unroll
  for (int j = 0; j < 4; ++j) {
    const int ccol = col0 + n0 + j*16 + l16;
    const float bvv = bias[ccol];
#pragma unroll
    for (int i = 0; i < 4; ++i) {
      const int crow = row0 + m0 + i*16 + quad*4;
#pragma unroll
      for (int r = 0; r < 4; ++r)
        C[(size_t)(crow + r)*N + ccol] = acc[i][j][r] + bvv;
    }
  }
}

// ---------------------------------------------------------------------------
// MFMA flash MQA attention (unchanged from R4: T12 in-register P exchange,
// 0 bank conflicts, LDS 36352).
// ---------------------------------------------------------------------------
#define KSTR 136
#define VSTR 72
__global__ __launch_bounds__(256) void mqa_attn_mfma(
    const __bf16* __restrict__ qb,   // [B*T][2048] rotated+scaled bf16
    const __bf16* __restrict__ kb,   // [B*T][128]  rotated bf16
    const __bf16* __restrict__ vt,   // [B][128][T] bf16 (V^T)
    __bf16* __restrict__ ctx)        // [B*T][2048] bf16
{
  __shared__ __bf16 Ks[64*KSTR];
  __shared__ __bf16 Vs[128*VSTR];
  __shared__ float  Linv[128];
  const int tid = threadIdx.x, lane = tid & 63, wave = tid >> 6;
  const int h5 = lane >> 5, l32 = lane & 31;
  const int h = blockIdx.y, b = blockIdx.z;
  const int qbase = blockIdx.x*128 + wave*32;

  bf16x8 qf[8];
  const __bf16* qp = qb + ((size_t)b*T_SEQ + qbase + l32)*DMODEL + h*HDIM;
#pragma unroll
  for (int ds = 0; ds < 8; ++ds) qf[ds] = *(const bf16x8*)(qp + ds*16 + h5*8);

  f32x16 oacc[4];
#pragma unroll
  for (int g = 0; g < 4; ++g)
#pragma unroll
    for (int r = 0; r < 16; ++r) oacc[g][r] = 0.f;
  float lsum = 0.f;

  const __bf16* kbase = kb + (size_t)b*T_SEQ*HDIM;
  const __bf16* vbase = vt + (size_t)b*HDIM*T_SEQ;

  for (int kt = 0; kt < T_SEQ/64; ++kt) {
    __syncthreads();
#pragma unroll
    for (int i = 0; i < 4; ++i) {
      int idx = i*256 + tid;
      int key = idx >> 4, c = idx & 15;
      *(bf16x8*)&Ks[key*KSTR + c*8] =
          *(const bf16x8*)(kbase + (size_t)(kt*64 + key)*HDIM + c*8);
    }
#pragma unroll
    for (int i = 0; i < 4; ++i) {
      int idx = i*256 + tid;
      int d = idx >> 3, c = idx & 7;
      *(bf16x8*)&Vs[d*VSTR + c*8] =
          *(const bf16x8*)(vbase + (size_t)d*T_SEQ + kt*64 + c*8);
    }
    __syncthreads();

    // ---- QK^T ------------------------------------------------------------
    f32x16 sacc[2];
#pragma unroll
    for (int kg = 0; kg < 2; ++kg) {
#pragma unroll
      for (int r = 0; r < 16; ++r) sacc[kg][r] = 0.f;
      __builtin_amdgcn_s_setprio(1);
#pragma unroll
      for (int ds = 0; ds < 8; ++ds) {
        bf16x8 kf = *(const bf16x8*)&Ks[(kg*32 + l32)*KSTR + ds*16 + h5*8];
        sacc[kg] = __builtin_amdgcn_mfma_f32_32x32x16_bf16(kf, qf[ds], sacc[kg], 0,0,0);
      }
      __builtin_amdgcn_s_setprio(0);
    }

    // ---- softmax + in-register P exchange (T12) --------------------------
    bf16x8 pf[4];
#pragma unroll
    for (int kg = 0; kg < 2; ++kg) {
      unsigned int w[8];
#pragma unroll
      for (int m = 0; m < 8; ++m) {
        float p0 = __builtin_amdgcn_exp2f(sacc[kg][2*m]);
        float p1 = __builtin_amdgcn_exp2f(sacc[kg][2*m+1]);
        lsum += p0; lsum += p1;
        w[m] = pack_bf16_2(p0, p1);
      }
#pragma unroll
      for (int kss = 0; kss < 2; ++kss) {
        auto s1 = __builtin_amdgcn_permlane32_swap(w[4*kss+0], w[4*kss+2], false, false);
        auto s2 = __builtin_amdgcn_permlane32_swap(w[4*kss+1], w[4*kss+3], false, false);
        uint32x4 u = (uint32x4){ s1[0], s2[0], s1[1], s2[1] };
        pf[kg*2 + kss] = __builtin_bit_cast(bf16x8, u);
      }
    }

    // ---- PV ---------------------------------------------------------------
    __builtin_amdgcn_s_setprio(1);
#pragma unroll
    for (int ks = 0; ks < 4; ++ks) {
#pragma unroll
      for (int g = 0; g < 4; ++g) {
        bf16x8 vf = *(const bf16x8*)&Vs[(g*32 + l32)*VSTR + ks*16 + h5*8];
        oacc[g] = __builtin_amdgcn_mfma_f32_32x32x16_bf16(pf[ks], vf, oacc[g], 0,0,0);
      }
    }
    __builtin_amdgcn_s_setprio(0);
  }

  lsum += __shfl_xor(lsum, 32);
  if (h5 == 0) Linv[wave*32 + l32] = 1.f / lsum;
  __asm__ volatile("s_waitcnt lgkmcnt(0)" ::: "memory");

  __bf16* op = ctx + ((size_t)b*T_SEQ + qbase)*DMODEL + h*HDIM + l32;
#pragma unroll
  for (int r1 = 0; r1 < 4; ++r1) {
    float4 iv = *(const float4*)&Linv[wave*32 + r1*8 + h5*4];
#pragma unroll
    for (int r0 = 0; r0 < 4; ++r0) {
      int qrow = r1*8 + h5*4 + r0;
#pragma unroll
      for (int g = 0; g < 4; ++g)
        op[(size_t)qrow*DMODEL + g*32] = (__bf16)(oacc[g][r1*4 + r0] * (&iv.x)[r0]);
    }
  }
}

// ---------------------------------------------------------------------------
extern "C" void kernel_launch(void* const* d_in, const int* in_sizes, int n_in,
                              void* d_out, int out_size, void* d_ws, size_t ws_size,
                              hipStream_t stream) {
  const float* x  = (const float*)d_in[0];
  const float* Wq = (const float*)d_in[1];
  const float* bq = (const float*)d_in[2];
  const float* Wk = (const float*)d_in[3];
  const float* bk = (const float*)d_in[4];
  const float* Wv = (const float*)d_in[5];
  const float* bv = (const float*)d_in[6];
  const float* Wo = (const float*)d_in[7];
  const float* bo = (const float*)d_in[8];
  float* out = (float*)d_out;

  uint8_t* ws = (uint8_t*)d_ws;
  __bf16* qrb  = (__bf16*)(ws);              // 16.78 MB rotated+scaled Q bf16
  __bf16* xb   = (__bf16*)(ws + 16777216);   // 16.78 MB x bf16; later ctx bf16
  __bf16* wqkvt= (__bf16*)(ws + 33554432);   //  9.44 MB [2304][2048]
  __bf16* wot  = (__bf16*)(ws + 42991616);   //  8.39 MB [2048][2048]
  __bf16* kbb  = (__bf16*)(ws + 51380224);   //  1.05 MB rotated K bf16
  __bf16* vbb  = (__bf16*)(ws + 52428800);   //  1.05 MB V bf16 [4096][128]
  __bf16* vtb  = (__bf16*)(ws + 53477376);   //  1.05 MB V^T bf16 [B][128][T]
  float2* rope = (float2*)(ws + 54525952);   //  1.05 MB cos/sin table
  float*  pout = (float*)(ws + 55574528);    // 67.1 MB fp32 [2][4096][2048]
  const size_t ws_needed = 55574528ull + 2ull*MROWS*DMODEL*4ull;  // ~122.7 MB

  const float qscale = 1.4426950408889634f * 0.08838834764831845f; // log2e/sqrt(128)

  // merged prep: rope (512) + cast (8192) + wtrans (8704) = 17408 blocks
  prep_kernel<<<dim3(17408), 256, 0, stream>>>(x, Wq, Wk, Wv, Wo, rope, xb, wqkvt, wot);

  // qkv: R4-exact 128x128, linear V (control arm)
  gemm_qkv_fused<<<dim3(18,32), 256, 0, stream>>>(
      xb, wqkvt, bq, bk, bv, rope, qrb, kbb, vbb, qscale);

  transpose_v_kernel<<<dim3(4,64,2), 256, 0, stream>>>(vbb, vtb);

  // attention reads qrb/kbb/vtb, writes bf16 ctx over xb (x is dead)
  mqa_attn_mfma<<<dim3(16,16,2), 256, 0, stream>>>(qrb, kbb, vtb, xb);

  if (ws_size >= ws_needed) {
    // out-GEMM split-K=2 (treatment): 1024 blocks = 4/CU, same panel traffic
    gemm_out_splitk<<<dim3(16,32,2), 256, 0, stream>>>(xb, wot, pout);
    reduce_out_kernel<<<dim3(MROWS*DMODEL/4/256), 256, 0, stream>>>(pout, bo, out);
  } else {
    gemm_bf16_t128<<<dim3(16,32), 256, 0, stream>>>(xb, wot, bo, out, MROWS, DMODEL, DMODEL);
  }
}

// Round 12
// 297.304 us; speedup vs baseline: 1.1354x; 1.1354x over previous
//
#include <hip/hip_runtime.h>
#include <math.h>

#define T_SEQ  2048
#define DMODEL 2048
#define NHEADS 16
#define HDIM   128
#define MROWS  4096   // B*T

typedef __attribute__((ext_vector_type(8)))  __bf16 bf16x8;
typedef __attribute__((ext_vector_type(4)))  __bf16 bf16x4;
typedef __attribute__((ext_vector_type(4)))  float  f32x4;
typedef __attribute__((ext_vector_type(16))) float  f32x16;
typedef __attribute__((ext_vector_type(4)))  unsigned int uint32x4;

#define GLOBAL_AS __attribute__((address_space(1)))
#define LDS_AS    __attribute__((address_space(3)))
__device__ __forceinline__ void async_copy16(const __bf16* g, __bf16* l) {
  // 16B/lane, LDS dest = wave-uniform base + lane*16 (m97/m104 semantics)
  __builtin_amdgcn_global_load_lds((const GLOBAL_AS void*)g, (LDS_AS void*)l, 16, 0, 0);
}

// pack two fp32 -> one u32 of 2 bf16 (RNE via (__bf16) cast)
__device__ __forceinline__ unsigned int pack_bf16_2(float a, float b) {
  __bf16 x = (__bf16)a, y = (__bf16)b;
  unsigned short ux = __builtin_bit_cast(unsigned short, x);
  unsigned short uy = __builtin_bit_cast(unsigned short, y);
  return (unsigned int)ux | ((unsigned int)uy << 16);
}

// ---------------------------------------------------------------------------
// Merged prep kernel, region-dispatched by blockIdx.x (unchanged).
// ---------------------------------------------------------------------------
__global__ __launch_bounds__(256) void prep_kernel(
    const float* __restrict__ x,
    const float* __restrict__ Wq, const float* __restrict__ Wk,
    const float* __restrict__ Wv, const float* __restrict__ Wo,
    float2* __restrict__ rope, __bf16* __restrict__ xb,
    __bf16* __restrict__ wqkvt, __bf16* __restrict__ wot)
{
  __shared__ float t[32][33];
  const int bid = blockIdx.x;
  const int tid = threadIdx.x;

  if (bid < 512) {                       // ---- RoPE table ----
    int idx = bid*256 + tid;             // 2048*64 entries
    int d = idx & 63, pos = idx >> 6;
    double freq = pow(10000.0, -(double)d / 64.0);
    double ang = (double)pos * freq;
    rope[idx] = make_float2((float)cos(ang), (float)sin(ang));
    return;
  }
  if (bid < 512 + 8192) {                // ---- x fp32 -> bf16 ----
    int i = (bid - 512)*256 + tid;       // n4 = 4096*2048/4 = 2097152 exactly
    float4 v = ((const float4*)x)[i];
    bf16x4 o = { (__bf16)v.x, (__bf16)v.y, (__bf16)v.z, (__bf16)v.w };
    *(bf16x4*)(xb + (size_t)i*4) = o;
    return;
  }
  // ---- weight transpose-cast (region grid 136 x 64) ----
  const int lb = bid - (512 + 8192);     // [0, 8704)
  const int by = lb / 136;               // row-tile 0..63
  const int bx = lb - by*136;            // col/region tile 0..135
  const float* src; __bf16* dst; int istride, c0, orow;
  if (bx < 64)       { src = Wq; istride = 2048; c0 = bx*32;      orow = c0;        dst = wqkvt; }
  else if (bx < 68)  { src = Wk; istride = 128;  c0 = (bx-64)*32; orow = 2048 + c0; dst = wqkvt; }
  else if (bx < 72)  { src = Wv; istride = 128;  c0 = (bx-68)*32; orow = 2176 + c0; dst = wqkvt; }
  else               { src = Wo; istride = 2048; c0 = (bx-72)*32; orow = c0;        dst = wot; }
  const int tx = tid & 31, ty = tid >> 5;
  const int r0 = by*32;
#pragma unroll
  for (int i = 0; i < 4; ++i)
    t[ty + i*8][tx] = src[(size_t)(r0 + ty + i*8)*istride + c0 + tx];
  __syncthreads();
#pragma unroll
  for (int i = 0; i < 4; ++i)
    dst[(size_t)(orow + ty + i*8)*2048 + r0 + tx] = (__bf16)t[tx][ty + i*8];
}

// ---------------------------------------------------------------------------
// bf16 -> bf16 transpose for V: in [B][2048][128] -> out [B][128][2048].
// ---------------------------------------------------------------------------
__global__ void transpose_v_kernel(const __bf16* __restrict__ in,
                                   __bf16* __restrict__ out) {
  __shared__ __bf16 t[32][34];
  const int bz = blockIdx.z;
  in  += (size_t)bz * 2048 * 128;
  out += (size_t)bz * 128 * 2048;
  const int tx = threadIdx.x & 31, ty = threadIdx.x >> 5;
  const int r0 = blockIdx.y*32, c0 = blockIdx.x*32;
#pragma unroll
  for (int i = 0; i < 4; ++i)
    t[ty + i*8][tx] = in[(size_t)(r0 + ty + i*8)*128 + c0 + tx];
  __syncthreads();
#pragma unroll
  for (int i = 0; i < 4; ++i)
    out[(size_t)(c0 + ty + i*8)*2048 + r0 + tx] = t[tx][ty + i*8];
}

// ---------------------------------------------------------------------------
// Fused QKV GEMM — R12 (= R11, unmeasured due to infra failure): R4-exact
// body; 1D grid (576) with BALANCED 2D XCD-chunked block mapping. XCD x
// (= blockIdx%8, round-robin dispatch, m192-verified) owns an 8-row x 9-col
// tile region: live working set = 8 A-row-panels (4.2 MB) + 9 B-col-panels
// (4.7 MB) = 8.9 MB instead of 18 MB (all-A + ~2.5 B cols under the default
// x-fastest mapping). Targets the measured law dur ~= FETCH/1.4TB/s + 18us
// (R5-R9: FETCH 107 MB = cross-XCD panel re-fetch; schedule changes never
// moved it).
// ---------------------------------------------------------------------------
__global__ __launch_bounds__(256) void gemm_qkv_fused(
    const __bf16* __restrict__ A,      // xb [4096][2048]
    const __bf16* __restrict__ Bt,     // wqkvt [2304][2048]
    const float* __restrict__ bq, const float* __restrict__ bk,
    const float* __restrict__ bv,
    const float2* __restrict__ rope,   // [2048][64]
    __bf16* __restrict__ qrb,          // [4096][2048]
    __bf16* __restrict__ kbb,          // [4096][128]
    __bf16* __restrict__ vbb,          // [4096][128]
    float qscale)
{
  __shared__ __bf16 As[128*32];
  __shared__ __bf16 Bs[128*32];
  // 576 blocks = 32 rows x 18 cols. XCD x -> region rows[rx*8,+8) x cols[cx*9,+9)
  const int orig = blockIdx.x;
  const int xcd = orig & 7, s = orig >> 3;       // s in [0,72)
  const int rx = xcd >> 1, cx = xcd & 1;
  const int lr = s & 7, lc = s >> 3;             // lr in [0,8), lc in [0,9)
  const int by = rx*8 + lr, bx = cx*9 + lc;
  const int tid = threadIdx.x;
  const int lane = tid & 63, wave = tid >> 6;
  const int quad = lane >> 4, l16 = lane & 15;
  const int m0 = (wave >> 1)*64, n0 = (wave & 1)*32;
  const int row0 = by*128, col0 = bx*128;
  const int srow = lane >> 2, scol = (lane & 3)*8;

  f32x4 acc[4][4];
#pragma unroll
  for (int i = 0; i < 4; ++i)
#pragma unroll
    for (int j = 0; j < 4; ++j) acc[i][j] = (f32x4){0.f,0.f,0.f,0.f};

  const __bf16* Ag = A  + (size_t)(row0 + wave*32 + srow)*DMODEL + scol;
  const __bf16* Bg = Bt + (size_t)(col0 + wave*32 + srow)*DMODEL + scol;
  __bf16* AsW = &As[wave*1024];
  __bf16* BsW = &Bs[wave*1024];

  for (int kk = 0; kk < DMODEL; kk += 32) {
    __syncthreads();
    async_copy16(Ag + kk,                     AsW);
    async_copy16(Ag + kk + (size_t)16*DMODEL, AsW + 512);
    async_copy16(Bg + kk,                     BsW);
    async_copy16(Bg + kk + (size_t)16*DMODEL, BsW + 512);
    __syncthreads();
    bf16x8 af[4], bfr[4];
#pragma unroll
    for (int i = 0; i < 4; ++i)
      af[i] = *(const bf16x8*)&As[(m0 + i*16 + l16)*32 + quad*8];
#pragma unroll
    for (int j = 0; j < 4; ++j) {
      const int cb = n0 + (j & 1)*16 + (j >> 1)*64;   // remapped column base
      bfr[j] = *(const bf16x8*)&Bs[(cb + l16)*32 + quad*8];
    }
#pragma unroll
    for (int i = 0; i < 4; ++i)
#pragma unroll
      for (int j = 0; j < 4; ++j)
        acc[i][j] = __builtin_amdgcn_mfma_f32_16x16x32_bf16(af[i], bfr[j], acc[i][j], 0,0,0);
  }

  // ---- fused epilogue: bias + RoPE + scale + bf16 store -------------------
  const float* bias_p; float scale; bool rot; __bf16* obase; int ostride;
  if (bx < 16)      { bias_p = bq + bx*128; scale = qscale; rot = true;
                      obase = qrb + bx*128; ostride = 2048; }
  else if (bx == 16){ bias_p = bk; scale = 1.f; rot = true;
                      obase = kbb; ostride = 128; }
  else              { bias_p = bv; scale = 1.f; rot = false;
                      obase = vbb; ostride = 128; }

#pragma unroll
  for (int j = 0; j < 2; ++j) {
    const int d = n0 + j*16 + l16;        // 0..63 within the 128-wide region
    const float b1 = bias_p[d], b2 = bias_p[d + 64];
#pragma unroll
    for (int i = 0; i < 4; ++i) {
      const int rl = m0 + i*16 + quad*4;
#pragma unroll
      for (int r = 0; r < 4; ++r) {
        const int rg = row0 + rl + r;
        const float x1 = acc[i][j][r]   + b1;
        const float x2 = acc[i][j+2][r] + b2;
        float c = 1.f, s2 = 0.f;
        if (rot) { float2 cs = rope[(size_t)(rg & (T_SEQ-1))*64 + d]; c = cs.x; s2 = cs.y; }
        obase[(size_t)rg*ostride + d]      = (__bf16)((x1*c - x2*s2)*scale);
        obase[(size_t)rg*ostride + d + 64] = (__bf16)((x2*c + x1*s2)*scale);
      }
    }
  }
}

// ---------------------------------------------------------------------------
// m97-style bf16 MFMA GEMM — R12: R4-exact body; 1D grid (512) with balanced
// 2D XCD chunking (8 rows x 8 cols per XCD; footprint 8.3 MB vs 18 MB).
// C = A@B + bias, fp32 out. Fixed problem shape M=4096, N=K=2048.
// ---------------------------------------------------------------------------
__global__ __launch_bounds__(256) void gemm_bf16_t128(
    const __bf16* __restrict__ A, const __bf16* __restrict__ Bt,
    const float* __restrict__ bias, float* __restrict__ C)
{
  __shared__ __bf16 As[128*32];
  __shared__ __bf16 Bs[128*32];
  // 512 blocks = 32 rows x 16 cols. XCD x -> rows[rx*8,+8) x cols[cx*8,+8)
  const int orig = blockIdx.x;
  const int xcd = orig & 7, s = orig >> 3;       // s in [0,64)
  const int rx = xcd >> 1, cx = xcd & 1;
  const int lr = s & 7, lc = s >> 3;             // both in [0,8)
  const int by = rx*8 + lr, bx = cx*8 + lc;
  const int K = DMODEL, N = DMODEL;
  const int tid = threadIdx.x;
  const int lane = tid & 63, wave = tid >> 6;
  const int quad = lane >> 4, l16 = lane & 15;
  const int m0 = (wave & 1)*64, n0 = (wave >> 1)*64;
  const int row0 = by*128, col0 = bx*128;
  const int srow = lane >> 2, scol = (lane & 3)*8;

  f32x4 acc[4][4];
#pragma unroll
  for (int i = 0; i < 4; ++i)
#pragma unroll
    for (int j = 0; j < 4; ++j) acc[i][j] = (f32x4){0.f,0.f,0.f,0.f};

  const __bf16* Ag = A  + (size_t)(row0 + wave*32 + srow)*K + scol;
  const __bf16* Bg = Bt + (size_t)(col0 + wave*32 + srow)*K + scol;
  __bf16* AsW = &As[wave*1024];
  __bf16* BsW = &Bs[wave*1024];

  for (int kk = 0; kk < K; kk += 32) {
    __syncthreads();
    async_copy16(Ag + kk,              AsW);
    async_copy16(Ag + kk + (size_t)16*K, AsW + 512);
    async_copy16(Bg + kk,              BsW);
    async_copy16(Bg + kk + (size_t)16*K, BsW + 512);
    __syncthreads();
    bf16x8 af[4], bfr[4];
#pragma unroll
    for (int i = 0; i < 4; ++i)
      af[i] = *(const bf16x8*)&As[(m0 + i*16 + l16)*32 + quad*8];
#pragma unroll
    for (int j = 0; j < 4; ++j)
      bfr[j] = *(const bf16x8*)&Bs[(n0 + j*16 + l16)*32 + quad*8];
#pragma unroll
    for (int i = 0; i < 4; ++i)
#pragma unroll
      for (int j = 0; j < 4; ++j)
        acc[i][j] = __builtin_amdgcn_mfma_f32_16x16x32_bf16(af[i], bfr[j], acc[i][j], 0,0,0);
  }
#pragma unroll
  for (int j = 0; j < 4; ++j) {
    const int ccol = col0 + n0 + j*16 + l16;
    const float bvv = bias[ccol];
#pragma unroll
    for (int i = 0; i < 4; ++i) {
      const int crow = row0 + m0 + i*16 + quad*4;
#pragma unroll
      for (int r = 0; r < 4; ++r)
        C[(size_t)(crow + r)*N + ccol] = acc[i][j][r] + bvv;
    }
  }
}

// ---------------------------------------------------------------------------
// MFMA flash MQA attention (unchanged from R4: T12 in-register P exchange,
// 0 bank conflicts, LDS 36352).
// ---------------------------------------------------------------------------
#define KSTR 136
#define VSTR 72
__global__ __launch_bounds__(256) void mqa_attn_mfma(
    const __bf16* __restrict__ qb,   // [B*T][2048] rotated+scaled bf16
    const __bf16* __restrict__ kb,   // [B*T][128]  rotated bf16
    const __bf16* __restrict__ vt,   // [B][128][T] bf16 (V^T)
    __bf16* __restrict__ ctx)        // [B*T][2048] bf16
{
  __shared__ __bf16 Ks[64*KSTR];
  __shared__ __bf16 Vs[128*VSTR];
  __shared__ float  Linv[128];
  const int tid = threadIdx.x, lane = tid & 63, wave = tid >> 6;
  const int h5 = lane >> 5, l32 = lane & 31;
  const int h = blockIdx.y, b = blockIdx.z;
  const int qbase = blockIdx.x*128 + wave*32;

  bf16x8 qf[8];
  const __bf16* qp = qb + ((size_t)b*T_SEQ + qbase + l32)*DMODEL + h*HDIM;
#pragma unroll
  for (int ds = 0; ds < 8; ++ds) qf[ds] = *(const bf16x8*)(qp + ds*16 + h5*8);

  f32x16 oacc[4];
#pragma unroll
  for (int g = 0; g < 4; ++g)
#pragma unroll
    for (int r = 0; r < 16; ++r) oacc[g][r] = 0.f;
  float lsum = 0.f;

  const __bf16* kbase = kb + (size_t)b*T_SEQ*HDIM;
  const __bf16* vbase = vt + (size_t)b*HDIM*T_SEQ;

  for (int kt = 0; kt < T_SEQ/64; ++kt) {
    __syncthreads();
#pragma unroll
    for (int i = 0; i < 4; ++i) {
      int idx = i*256 + tid;
      int key = idx >> 4, c = idx & 15;
      *(bf16x8*)&Ks[key*KSTR + c*8] =
          *(const bf16x8*)(kbase + (size_t)(kt*64 + key)*HDIM + c*8);
    }
#pragma unroll
    for (int i = 0; i < 4; ++i) {
      int idx = i*256 + tid;
      int d = idx >> 3, c = idx & 7;
      *(bf16x8*)&Vs[d*VSTR + c*8] =
          *(const bf16x8*)(vbase + (size_t)d*T_SEQ + kt*64 + c*8);
    }
    __syncthreads();

    // ---- QK^T ------------------------------------------------------------
    f32x16 sacc[2];
#pragma unroll
    for (int kg = 0; kg < 2; ++kg) {
#pragma unroll
      for (int r = 0; r < 16; ++r) sacc[kg][r] = 0.f;
      __builtin_amdgcn_s_setprio(1);
#pragma unroll
      for (int ds = 0; ds < 8; ++ds) {
        bf16x8 kf = *(const bf16x8*)&Ks[(kg*32 + l32)*KSTR + ds*16 + h5*8];
        sacc[kg] = __builtin_amdgcn_mfma_f32_32x32x16_bf16(kf, qf[ds], sacc[kg], 0,0,0);
      }
      __builtin_amdgcn_s_setprio(0);
    }

    // ---- softmax + in-register P exchange (T12) --------------------------
    bf16x8 pf[4];
#pragma unroll
    for (int kg = 0; kg < 2; ++kg) {
      unsigned int w[8];
#pragma unroll
      for (int m = 0; m < 8; ++m) {
        float p0 = __builtin_amdgcn_exp2f(sacc[kg][2*m]);
        float p1 = __builtin_amdgcn_exp2f(sacc[kg][2*m+1]);
        lsum += p0; lsum += p1;
        w[m] = pack_bf16_2(p0, p1);
      }
#pragma unroll
      for (int kss = 0; kss < 2; ++kss) {
        auto s1 = __builtin_amdgcn_permlane32_swap(w[4*kss+0], w[4*kss+2], false, false);
        auto s2 = __builtin_amdgcn_permlane32_swap(w[4*kss+1], w[4*kss+3], false, false);
        uint32x4 u = (uint32x4){ s1[0], s2[0], s1[1], s2[1] };
        pf[kg*2 + kss] = __builtin_bit_cast(bf16x8, u);
      }
    }

    // ---- PV ---------------------------------------------------------------
    __builtin_amdgcn_s_setprio(1);
#pragma unroll
    for (int ks = 0; ks < 4; ++ks) {
#pragma unroll
      for (int g = 0; g < 4; ++g) {
        bf16x8 vf = *(const bf16x8*)&Vs[(g*32 + l32)*VSTR + ks*16 + h5*8];
        oacc[g] = __builtin_amdgcn_mfma_f32_32x32x16_bf16(pf[ks], vf, oacc[g], 0,0,0);
      }
    }
    __builtin_amdgcn_s_setprio(0);
  }

  lsum += __shfl_xor(lsum, 32);
  if (h5 == 0) Linv[wave*32 + l32] = 1.f / lsum;
  __asm__ volatile("s_waitcnt lgkmcnt(0)" ::: "memory");

  __bf16* op = ctx + ((size_t)b*T_SEQ + qbase)*DMODEL + h*HDIM + l32;
#pragma unroll
  for (int r1 = 0; r1 < 4; ++r1) {
    float4 iv = *(const float4*)&Linv[wave*32 + r1*8 + h5*4];
#pragma unroll
    for (int r0 = 0; r0 < 4; ++r0) {
      int qrow = r1*8 + h5*4 + r0;
#pragma unroll
      for (int g = 0; g < 4; ++g)
        op[(size_t)qrow*DMODEL + g*32] = (__bf16)(oacc[g][r1*4 + r0] * (&iv.x)[r0]);
    }
  }
}

// ---------------------------------------------------------------------------
extern "C" void kernel_launch(void* const* d_in, const int* in_sizes, int n_in,
                              void* d_out, int out_size, void* d_ws, size_t ws_size,
                              hipStream_t stream) {
  const float* x  = (const float*)d_in[0];
  const float* Wq = (const float*)d_in[1];
  const float* bq = (const float*)d_in[2];
  const float* Wk = (const float*)d_in[3];
  const float* bk = (const float*)d_in[4];
  const float* Wv = (const float*)d_in[5];
  const float* bv = (const float*)d_in[6];
  const float* Wo = (const float*)d_in[7];
  const float* bo = (const float*)d_in[8];
  float* out = (float*)d_out;

  uint8_t* ws = (uint8_t*)d_ws;
  __bf16* qrb  = (__bf16*)(ws);              // 16.78 MB rotated+scaled Q bf16
  __bf16* xb   = (__bf16*)(ws + 16777216);   // 16.78 MB x bf16; later ctx bf16
  __bf16* wqkvt= (__bf16*)(ws + 33554432);   //  9.44 MB [2304][2048]
  __bf16* wot  = (__bf16*)(ws + 42991616);   //  8.39 MB [2048][2048]
  __bf16* kbb  = (__bf16*)(ws + 51380224);   //  1.05 MB rotated K bf16
  __bf16* vbb  = (__bf16*)(ws + 52428800);   //  1.05 MB V bf16 [4096][128]
  __bf16* vtb  = (__bf16*)(ws + 53477376);   //  1.05 MB V^T bf16 [B][128][T]
  float2* rope = (float2*)(ws + 54525952);   //  1.05 MB cos/sin table

  const float qscale = 1.4426950408889634f * 0.08838834764831845f; // log2e/sqrt(128)

  // merged prep: rope (512) + cast (8192) + wtrans (8704) = 17408 blocks
  prep_kernel<<<dim3(17408), 256, 0, stream>>>(x, Wq, Wk, Wv, Wo, rope, xb, wqkvt, wot);

  // qkv: R4 body, 1D grid 576 with balanced 2D XCD chunking
  gemm_qkv_fused<<<dim3(576), 256, 0, stream>>>(
      xb, wqkvt, bq, bk, bv, rope, qrb, kbb, vbb, qscale);

  transpose_v_kernel<<<dim3(4,64,2), 256, 0, stream>>>(vbb, vtb);

  // attention reads qrb/kbb/vtb, writes bf16 ctx over xb (x is dead)
  mqa_attn_mfma<<<dim3(16,16,2), 256, 0, stream>>>(qrb, kbb, vtb, xb);

  // out-GEMM: R4 body, 1D grid 512 with balanced 2D XCD chunking
  gemm_bf16_t128<<<dim3(512), 256, 0, stream>>>(xb, wot, bo, out);
}